// Round 6
// baseline (366810.059 us; speedup 1.0000x reference)
//
#include <hip/hip_runtime.h>
#include <hip/hip_bf16.h>

// Persistent cooperative RNN kernel for MI355X (gfx950) — epoch-tagged
// dataflow, minimum-leg topology (5 critical cross-WG legs per step).
// 256 WGs x 512 threads, 1 WG/CU (~154KB LDS). Each WG owns 4 hidden rows =>
// 16 gate rows of every 4H weight matrix. Cross-WG values (enc h/c, dhx, dh1,
// dh2, dh3) are 8-byte (f32 value, u32 epoch) pairs written with agent-scope
// 64-bit atomic stores, consumed by polling coherent (sc0 sc1) 16B loads.
// The small matvecs ds_i = clsW@dh_i and f_i = relu(futW@dh_i) are computed
// LOCALLY by every WG from the dh_i it already polls for the decoder
// recurrence (zero extra legs). Thread (s=tid>>6, o=tid&63) holds 128 bf16
// columns of clsW/futW row o in registers (64+64 packed u32), plus 2 fusW
// rows (64 u32): ~192 persistent VGPRs/thread.
// ROUND-6 REGISTER FIX (the spill saga, rounds 2-5):
//   r2: __launch_bounds__(512,2) sets only MIN waves/EU -> allocator targeted
//       4 waves/EU (128 VGPR) and spilled 307GB of scratch FETCH.
//   r3: amdgpu_waves_per_eu(2,2) has the needed max, but run<> was a separate
//       function -> kernel-level attrs never governed its allocation.
//   r5: __forceinline__ proven effective (VGPR changed) but no occupancy attr
//       -> heuristic chose 64 VGPR (32-wave target, ignoring the LDS cap).
// This round combines ALL THREE: 512 threads + __forceinline__ run +
// amdgpu_waves_per_eu(2,2). max=2 waves/EU == what LDS already forces
// (1 WG/CU, 8 waves), raising the budget to 256 VGPRs where demand (~222)
// fits. Occupancy is unchanged vs the 53.6ms baseline.

typedef unsigned short u16t;
typedef unsigned int u32t;
typedef unsigned long long u64t;

#define TSTEPS 2045
#define NWG 256
#define NTHR 512
#define SPINCAP 8192

// d_ws float offsets (all pair arrays: 2 floats per element)
#define HENC  0        // [par][1024 pairs]  enc h
#define CENC  4096     // [par][1024 pairs]  enc c
#define DHX   8192     // [par][1024 pairs]  head dhx
#define DD1   12288    // [par][1024 pairs]  dec h1
#define DD2   16384    // [par][1024 pairs]  dec h2
#define DD3   20480    // [par][1024 pairs]  dec h3

struct Params {
  const void *X, *eWih, *eWhh, *ebih, *ebhh, *dWih, *dWhh, *dbih, *dbhh,
             *hxW, *hxb, *cxW, *cxb, *fusW, *fusb_g, *futW, *futb_g, *clsW, *clsb_g;
  float* ws;
  void* out;
};

struct SharedMem {
  alignas(16) float encW[16 * 1152];   // [row][Wih(128)|Whh(1024)] f32, 73728B
  alignas(16) u16t  decW[16 * 2048];   // [row][Wih(1024)|Whh(1024)] bf16, 65536B
  alignas(16) float xs[2048];          // staged vectors for dots
  alignas(16) float dh3buf[1024];      // dh3(prev) at R1; h stash for w8-15 at R2
  alignas(16) float redc[8][64];       // in-WG split-K reduce buffers
  alignas(16) float redf[8][64];
  alignas(16) float xsf[128];          // R1 fusion input [x(64)|fut(64)]
  float clsb[64], futb[64], fut_acc[64], dsbuf[64], xnext[64];
  float bias_e[16], bias_d[16], g16[16];
  float dcx_s[4], encc[4], hxb4[4], cxb4[4];
  int bail;
  int badcnt;
};

__device__ __forceinline__ float bfu(u16t u){
  union { u32t i; float f; } v; v.i = ((u32t)u) << 16; return v.f;
}
__device__ __forceinline__ u32t fbits(float f){
  union { float f; u32t u; } c; c.f = f; return c.u;
}
__device__ __forceinline__ u16t bf16bits(float v){
  __hip_bfloat16 b = __float2bfloat16(v);
  union { __hip_bfloat16 b; u16t u; } c; c.b = b; return c.u;
}
template<bool F32>
__device__ __forceinline__ float ldE(const void* p, int i){
  if (F32) return ((const float*)p)[i];
  return bfu(((const u16t*)p)[i]);
}
template<bool F32>
__device__ __forceinline__ u16t ldB(const void* p, int i){
  if (F32) return bf16bits(((const float*)p)[i]);
  return ((const u16t*)p)[i];
}
template<bool F32>
__device__ __forceinline__ void stO(void* p, int i, float v){
  if (F32) ((float*)p)[i] = v;
  else     ((u16t*)p)[i] = bf16bits(v);
}
__device__ __forceinline__ float sigm(float x){ return 1.f / (1.f + __expf(-x)); }
__device__ __forceinline__ float tanhx(float x){
  float e = __expf(-2.f * fabsf(x));
  float t = (1.f - e) / (1.f + e);
  return copysignf(t, x);
}
// Tagged-pair store: (value, epoch) as one 64-bit agent-scope atomic.
__device__ __forceinline__ void stp(float* rowbase, int idx, float v, u32t ep){
  u64t u = (u64t)fbits(v) | ((u64t)ep << 32);
  __hip_atomic_store((u64t*)rowbase + idx, u,
                     __ATOMIC_RELAXED, __HIP_MEMORY_SCOPE_AGENT);
}
// Coherent 16B load (device coherence point).
__device__ __forceinline__ float4 ld4c(const float* p){
  float4 r;
  asm volatile("global_load_dwordx4 %0, %1, off sc0 sc1\n\t"
               "s_waitcnt vmcnt(0)"
               : "=&v"(r) : "v"(p) : "memory");
  return r;
}
// Two coherent 16B loads, single wait.
__device__ __forceinline__ void ld4c2(const float* p0, const float* p1,
                                      float4& a, float4& b){
  asm volatile(
    "global_load_dwordx4 %0, %2, off sc0 sc1\n\t"
    "global_load_dwordx4 %1, %3, off sc0 sc1\n\t"
    "s_waitcnt vmcnt(0)"
    : "=&v"(a), "=&v"(b)
    : "v"(p0), "v"(p1)
    : "memory");
}
// Poll one quad (2 tagged pairs) until both tags == ep.
__device__ __forceinline__ float2 poll2(const float* q, u32t ep, int* bail){
  float4 r; int sp = 0;
  for (;;){
    r = ld4c(q);
    if (fbits(r.y) == ep && fbits(r.w) == ep) break;
    if (*bail) break;
    if (++sp > SPINCAP){ *bail = 1; break; }
  }
  return float2{r.x, r.z};
}

// Half-wave (32 lanes) dot of GLOBAL weight row with f32 x (LDS), reduced.
template<bool F32>
__device__ __forceinline__ float hw_dot(const void* wbase, long off,
                                        const float* __restrict__ x,
                                        int K, int lane){
  float acc = 0.f;
  if (F32){
    const float* w = (const float*)wbase + off;
    for (int c = lane * 4; c < K; c += 128){
      float4 wv = *(const float4*)(w + c);
      float4 xv = *(const float4*)(x + c);
      acc = fmaf(wv.x, xv.x, acc); acc = fmaf(wv.y, xv.y, acc);
      acc = fmaf(wv.z, xv.z, acc); acc = fmaf(wv.w, xv.w, acc);
    }
  } else {
    const u16t* w = (const u16t*)wbase + off;
    for (int c = lane * 4; c < K; c += 128){
      ushort4 wv = *(const ushort4*)(w + c);
      float4  xv = *(const float4*)(x + c);
      acc = fmaf(bfu(wv.x), xv.x, acc); acc = fmaf(bfu(wv.y), xv.y, acc);
      acc = fmaf(bfu(wv.z), xv.z, acc); acc = fmaf(bfu(wv.w), xv.w, acc);
    }
  }
  #pragma unroll
  for (int o = 16; o; o >>= 1) acc += __shfl_xor(acc, o, 64);
  return acc;
}

// Un-reduced per-lane dot partials (reduce once with wred).
__device__ __forceinline__ float dotnr_f32(const float* __restrict__ w,
                                           const float* __restrict__ x,
                                           int K, int lane){
  float acc = 0.f;
  for (int c = lane * 4; c < K; c += 128){
    float4 wv = *(const float4*)(w + c);
    float4 xv = *(const float4*)(x + c);
    acc = fmaf(wv.x, xv.x, acc); acc = fmaf(wv.y, xv.y, acc);
    acc = fmaf(wv.z, xv.z, acc); acc = fmaf(wv.w, xv.w, acc);
  }
  return acc;
}
__device__ __forceinline__ float dotnr_bf16(const u16t* __restrict__ w,
                                            const float* __restrict__ x,
                                            int K, int lane){
  float acc = 0.f;
  for (int c = lane * 8; c < K; c += 256){
    uint4  wv = *(const uint4*)(w + c);
    float4 x0 = *(const float4*)(x + c);
    float4 x1 = *(const float4*)(x + c + 4);
    acc = fmaf(bfu((u16t)(wv.x & 0xffff)), x0.x, acc);
    acc = fmaf(bfu((u16t)(wv.x >> 16)),    x0.y, acc);
    acc = fmaf(bfu((u16t)(wv.y & 0xffff)), x0.z, acc);
    acc = fmaf(bfu((u16t)(wv.y >> 16)),    x0.w, acc);
    acc = fmaf(bfu((u16t)(wv.z & 0xffff)), x1.x, acc);
    acc = fmaf(bfu((u16t)(wv.z >> 16)),    x1.y, acc);
    acc = fmaf(bfu((u16t)(wv.w & 0xffff)), x1.z, acc);
    acc = fmaf(bfu((u16t)(wv.w >> 16)),    x1.w, acc);
  }
  return acc;
}
__device__ __forceinline__ float wred(float a){
  #pragma unroll
  for (int o = 16; o; o >>= 1) a += __shfl_xor(a, o, 64);
  return a;
}

// 128-col dot of a register-resident bf16-packed row slice against LDS v.
// All lanes of a wave share the same v addresses -> LDS broadcast.
__device__ __forceinline__ float so_dot(const u32t* __restrict__ wr,
                                        const float* __restrict__ v){
  float a = 0.f;
  #pragma unroll
  for (int k = 0; k < 32; ++k){
    float4 x = *(const float4*)(v + 4 * k);
    u32t w0 = wr[2 * k], w1 = wr[2 * k + 1];
    a = fmaf(bfu((u16t)(w0 & 0xffff)), x.x, a);
    a = fmaf(bfu((u16t)(w0 >> 16)),    x.y, a);
    a = fmaf(bfu((u16t)(w1 & 0xffff)), x.z, a);
    a = fmaf(bfu((u16t)(w1 >> 16)),    x.w, a);
  }
  return a;
}
// Same, two matrices in one pass over v (cls + fut share the dh reads).
__device__ __forceinline__ void so_dot2(const u32t* __restrict__ wa,
                                        const u32t* __restrict__ wb,
                                        const float* __restrict__ v,
                                        float& ra, float& rb){
  float a = 0.f, b = 0.f;
  #pragma unroll
  for (int k = 0; k < 32; ++k){
    float4 x = *(const float4*)(v + 4 * k);
    u32t a0 = wa[2 * k], a1 = wa[2 * k + 1];
    u32t b0 = wb[2 * k], b1 = wb[2 * k + 1];
    a = fmaf(bfu((u16t)(a0 & 0xffff)), x.x, a);
    a = fmaf(bfu((u16t)(a0 >> 16)),    x.y, a);
    a = fmaf(bfu((u16t)(a1 & 0xffff)), x.z, a);
    a = fmaf(bfu((u16t)(a1 >> 16)),    x.w, a);
    b = fmaf(bfu((u16t)(b0 & 0xffff)), x.x, b);
    b = fmaf(bfu((u16t)(b0 >> 16)),    x.y, b);
    b = fmaf(bfu((u16t)(b1 & 0xffff)), x.z, b);
    b = fmaf(bfu((u16t)(b1 >> 16)),    x.w, b);
  }
  ra = a; rb = b;
}
__device__ __forceinline__ float red8(const float (*r)[64], int o){
  return ((r[0][o] + r[1][o]) + (r[2][o] + r[3][o]))
       + ((r[4][o] + r[5][o]) + (r[6][o] + r[7][o]));
}

template<bool F32>
__device__ __forceinline__ void run(const Params& p, SharedMem& S){
  const int tid  = threadIdx.x;
  const int w    = blockIdx.x;
  const int hw   = tid >> 5;            // half-wave 0..15 -> one gate row each
  const int lane = tid & 31;
  const int so_s = tid >> 6;            // in-WG split-K slice (0..7, = wave id)
  const int so_o = tid & 63;            // output row this thread accumulates
  const long grow = (long)((hw >> 2) * 1024 + 4 * w + (hw & 3));  // gate row
  float* ws = p.ws;

  // ---------- startup: stage per-WG weights into LDS ----------
  {
    float* er = S.encW + hw * 1152;
    for (int c = lane; c < 128; c += 32)  er[c]       = ldE<F32>(p.eWih, (int)(grow * 128 + c));
    for (int c = lane; c < 1024; c += 32) er[128 + c] = ldE<F32>(p.eWhh, (int)(grow * 1024 + c));
    u16t* dr = S.decW + hw * 2048;
    for (int c = lane; c < 1024; c += 32){
      dr[c]        = ldB<F32>(p.dWih, (int)(grow * 1024 + c));
      dr[1024 + c] = ldB<F32>(p.dWhh, (int)(grow * 1024 + c));
    }
  }
  // fus_W rows for this thread's two fusion outputs -> registers
  u32t fw[64];
  float fusb0, fusb1;
  {
    int h0 = 2 * tid, h1 = 2 * tid + 1;
    #pragma unroll
    for (int o = 0; o < 64; ++o){
      u16t lo = ldB<F32>(p.fusW, h0 * 64 + o);
      u16t hi = ldB<F32>(p.fusW, h1 * 64 + o);
      fw[o] = ((u32t)hi << 16) | lo;
    }
    fusb0 = ldE<F32>(p.fusb_g, h0);
    fusb1 = ldE<F32>(p.fusb_g, h1);
  }
  // clsW/futW row-o column slice [so_s*128, so_s*128+128) -> registers (bf16x2)
  u32t clsr[64], futr[64];
  {
    #pragma unroll
    for (int k = 0; k < 64; ++k){
      int base = so_o * 1024 + so_s * 128 + 2 * k;
      clsr[k] = ((u32t)ldB<F32>(p.clsW, base + 1) << 16) | ldB<F32>(p.clsW, base);
      futr[k] = ((u32t)ldB<F32>(p.futW, base + 1) << 16) | ldB<F32>(p.futW, base);
    }
  }
  if (tid < 64){
    S.clsb[tid] = ldE<F32>(p.clsb_g, tid);
    S.futb[tid] = ldE<F32>(p.futb_g, tid);
    S.fut_acc[tid] = 0.f;
  }
  if (tid < 16){
    int gr = (tid >> 2) * 1024 + 4 * w + (tid & 3);
    S.bias_e[tid] = ldE<F32>(p.ebih, gr) + ldE<F32>(p.ebhh, gr);
    S.bias_d[tid] = ldE<F32>(p.dbih, gr) + ldE<F32>(p.dbhh, gr);
  }
  if (tid < 4){
    S.hxb4[tid] = ldE<F32>(p.hxb, 4 * w + tid);
    S.cxb4[tid] = ldE<F32>(p.cxb, 4 * w + tid);
    S.encc[tid] = 0.f;
  }
  float enc_pre = 0.f;   // per-lane partial of encWhh @ h(t-1); h(-1)=0
  __syncthreads();

  for (int t = 0; t < TSTEPS; ++t){
    const int  par  = t & 1;
    const int  ppar = par ^ 1;
    const u32t ep   = (u32t)(t + 1);
    const u32t epv  = (u32t)t;            // tag of previous step's values

    // ============ R1: f3 local from dh3(prev); encoder gates ============
    if (tid < 64){
      S.xsf[tid] = (t == 0) ? ldE<F32>(p.X, tid) : S.xnext[tid];
      if (t == 0) S.xsf[64 + tid] = 0.f;
    }
    if (t > 0){
      float2 v = poll2(ws + DD3 + ppar * 2048 + tid * 4, epv, &S.bail);
      S.dh3buf[2 * tid] = v.x; S.dh3buf[2 * tid + 1] = v.y;
      __syncthreads();
      S.redf[so_s][so_o] = so_dot(futr, S.dh3buf + so_s * 128);
      __syncthreads();
      if (tid < 64){
        float f3 = fmaxf(red8(S.redf, tid) + S.futb[tid], 0.f);
        S.xsf[64 + tid] = (S.fut_acc[tid] + f3) * (1.f / 3.f);
        S.fut_acc[tid] = 0.f;
      }
    }
    __syncthreads();
    {
      float a = wred(enc_pre + dotnr_f32(S.encW + hw * 1152, S.xsf, 128, lane))
              + S.bias_e[hw];
      if (lane == 0) S.g16[hw] = a;
    }
    __syncthreads();
    if (tid < 4){
      float gi = sigm(S.g16[tid]), gf = sigm(S.g16[4 + tid]),
            gg = tanhx(S.g16[8 + tid]), go = sigm(S.g16[12 + tid]);
      float c = gf * S.encc[tid] + gi * gg;
      float h = go * tanhx(c);
      S.encc[tid] = c;
      stp(ws + HENC + par * 2048, 4 * w + tid, h, ep);
      stp(ws + CENC + par * 2048, 4 * w + tid, c, ep);
    }

    // ============ R2: heads dhx/dcx + enc_pre (merged h+c poll) ============
    {
      const float* ph_ = ws + HENC + par * 2048 + tid * 4;
      const float* pc_ = ws + CENC + par * 2048 + tid * 4;
      float4 a, b; int sp = 0;
      for (;;){
        ld4c2(ph_, pc_, a, b);
        if (fbits(a.y) == ep && fbits(a.w) == ep &&
            fbits(b.y) == ep && fbits(b.w) == ep) break;
        if (S.bail) break;
        if (++sp > SPINCAP){ S.bail = 1; break; }
      }
      S.xs[2 * tid] = a.x;        S.xs[2 * tid + 1] = a.z;
      S.xs[1024 + 2 * tid] = b.x; S.xs[1025 + 2 * tid] = b.z;
      if (w >= 8 && w < 16){       // stash h for R3-shadow enc_score
        S.dh3buf[2 * tid] = a.x; S.dh3buf[2 * tid + 1] = a.z;
      }
    }
    __syncthreads();
    if (hw < 4){
      float d = fmaxf(hw_dot<F32>(p.hxW, (long)(4 * w + hw) * 1024, S.xs, 1024, lane)
                      + S.hxb4[hw], 0.f);
      if (lane == 0) stp(ws + DHX + par * 2048, 4 * w + hw, d, ep);
    } else if (hw < 8){
      int j = hw - 4;
      float d = fmaxf(hw_dot<F32>(p.cxW, (long)(4 * w + j) * 1024, S.xs + 1024, 1024, lane)
                      + S.cxb4[j], 0.f);
      if (lane == 0) S.dcx_s[j] = d;   // decoder c, reused by all 3 iters (ref bug)
    }
    // next step's encoder Whh@h partial, in R2's shadow (after DHX stp)
    enc_pre = dotnr_f32(S.encW + hw * 1152 + 128, S.xs, 1024, lane);
    __syncthreads();   // protect xs/dh3buf readers from R3's staging overwrite

    // ============ R3: decoder iter 1 (fusion_in = 0) ============
    // w8-15: deferred enc_score in the DHX-poll shadow (h from stash)
    if (w >= 8 && w < 16 && hw >= 8){
      int r = (w - 8) * 8 + (hw - 8);
      float s = hw_dot<F32>(p.clsW, (long)r * 1024, S.dh3buf, 1024, lane) + S.clsb[r];
      if (lane == 0) stO<F32>(p.out, t * 64 + r, s);
    }
    {
      float2 v = poll2(ws + DHX + par * 2048 + tid * 4, ep, &S.bail);
      S.xs[2 * tid] = v.x; S.xs[2 * tid + 1] = v.y;
    }
    __syncthreads();
    {
      float a = wred(dotnr_bf16(S.decW + hw * 2048 + 1024, S.xs, 1024, lane))
              + S.bias_d[hw];
      if (lane == 0) S.g16[hw] = a;
    }
    __syncthreads();
    if (tid < 4){
      float gi = sigm(S.g16[tid]), gf = sigm(S.g16[4 + tid]),
            gg = tanhx(S.g16[8 + tid]), go = sigm(S.g16[12 + tid]);
      float c = gf * S.dcx_s[tid] + gi * gg;
      float h = go * tanhx(c);
      stp(ws + DD1 + par * 2048, 4 * w + tid, h, ep);
    }
    if (tid < 64)
      S.xnext[tid] = ldE<F32>(p.X, (t + 1) * 64 + tid);   // prefetch x(t+1)
    // w22: ds3(prev) output, computed in the DD1-poll shadow (dh3buf intact)
    if (t > 0 && w == 22){
      S.redc[so_s][so_o] = so_dot(clsr, S.dh3buf + so_s * 128);
      __syncthreads();
      if (tid < 64)
        stO<F32>(p.out, TSTEPS * 64 + ((t - 1) * 3 + 2) * 64 + tid,
                 red8(S.redc, tid) + S.clsb[tid]);
      __syncthreads();
    }

    // ============ R4/R5: decoder iters 2,3 (ds/f local, zero extra legs) ====
    for (int di = 2; di <= 3; ++di){
      {
        float2 v = poll2(ws + (di == 2 ? DD1 : DD2) + par * 2048 + tid * 4, ep, &S.bail);
        S.xs[1024 + 2 * tid] = v.x; S.xs[1025 + 2 * tid] = v.y;
      }
      __syncthreads();
      float accA = dotnr_bf16(S.decW + hw * 2048 + 1024, S.xs + 1024, 1024, lane);
      {
        float pc, pf;
        so_dot2(clsr, futr, S.xs + 1024 + so_s * 128, pc, pf);
        S.redc[so_s][so_o] = pc;
        S.redf[so_s][so_o] = pf;
      }
      __syncthreads();
      if (tid < 64){
        float sc = red8(S.redc, tid) + S.clsb[tid];
        float sf = fmaxf(red8(S.redf, tid) + S.futb[tid], 0.f);
        S.dsbuf[tid] = sc;
        S.fut_acc[tid] += sf;
        if (w == 20 + (di - 2))
          stO<F32>(p.out, TSTEPS * 64 + (t * 3 + (di - 2)) * 64 + tid, sc);
      }
      __syncthreads();
      {   // fusion_in = relu(fus_W @ ds + fus_b), per-thread 2 rows from VGPRs
        float a0 = fusb0, a1 = fusb1;
        #pragma unroll
        for (int o = 0; o < 64; ++o){
          float d = S.dsbuf[o];
          a0 = fmaf(bfu((u16t)(fw[o] & 0xffff)), d, a0);
          a1 = fmaf(bfu((u16t)(fw[o] >> 16)),    d, a1);
        }
        S.xs[2 * tid]     = fmaxf(a0, 0.f);
        S.xs[2 * tid + 1] = fmaxf(a1, 0.f);
      }
      __syncthreads();
      {
        float a = wred(accA + dotnr_bf16(S.decW + hw * 2048, S.xs, 1024, lane))
                + S.bias_d[hw];
        if (lane == 0) S.g16[hw] = a;
      }
      __syncthreads();
      if (tid < 4){
        float gi = sigm(S.g16[tid]), gf = sigm(S.g16[4 + tid]),
              gg = tanhx(S.g16[8 + tid]), go = sigm(S.g16[12 + tid]);
        float c = gf * S.dcx_s[tid] + gi * gg;
        float h = go * tanhx(c);
        stp(ws + (di == 2 ? DD2 : DD3) + par * 2048, 4 * w + tid, h, ep);
      }
    }
  }

  // epilogue: last step's ds3 (its consumer round never runs)
  if (w == 22){
    float2 v = poll2(ws + DD3 + ((TSTEPS - 1) & 1) * 2048 + tid * 4,
                     (u32t)TSTEPS, &S.bail);
    S.dh3buf[2 * tid] = v.x; S.dh3buf[2 * tid + 1] = v.y;
    __syncthreads();
    S.redc[so_s][so_o] = so_dot(clsr, S.dh3buf + so_s * 128);
    __syncthreads();
    if (tid < 64)
      stO<F32>(p.out, TSTEPS * 64 + ((TSTEPS - 1) * 3 + 2) * 64 + tid,
               red8(S.redc, tid) + S.clsb[tid]);
  }
}

__global__ __attribute__((amdgpu_flat_work_group_size(NTHR, NTHR),
                          amdgpu_waves_per_eu(2, 2)))
void trn_persist(Params p){
  __shared__ SharedMem S;
  // ---- runtime input-dtype detection from X's bit patterns ----
  if (threadIdx.x == 0){ S.bail = 0; S.badcnt = 0; }
  __syncthreads();
  if (threadIdx.x < 256){
    u16t u = ((const u16t*)p.X)[threadIdx.x];
    int e = (u >> 7) & 0xff;
    if (e == 0 || e >= 141) atomicAdd(&S.badcnt, 1);
  }
  __syncthreads();
  if (S.badcnt >= 3) run<true>(p, S);
  else               run<false>(p, S);
}

extern "C" void kernel_launch(void* const* d_in, const int* in_sizes, int n_in,
                              void* d_out, int out_size, void* d_ws, size_t ws_size,
                              hipStream_t stream){
  Params P;
  P.X      = d_in[0];
  P.eWih   = d_in[1];
  P.eWhh   = d_in[2];
  P.ebih   = d_in[3];
  P.ebhh   = d_in[4];
  P.dWih   = d_in[5];
  P.dWhh   = d_in[6];
  P.dbih   = d_in[7];
  P.dbhh   = d_in[8];
  P.hxW    = d_in[9];
  P.hxb    = d_in[10];
  P.cxW    = d_in[11];
  P.cxb    = d_in[12];
  P.fusW   = d_in[13];
  P.fusb_g = d_in[14];
  P.futW   = d_in[15];
  P.futb_g = d_in[16];
  P.clsW   = d_in[17];
  P.clsb_g = d_in[18];
  P.ws     = (float*)d_ws;
  P.out    = d_out;

  void* args[] = { &P };
  hipLaunchCooperativeKernel((void*)trn_persist, dim3(NWG), dim3(NTHR),
                             args, 0, stream);
}

// Round 7
// 57368.359 us; speedup vs baseline: 6.3939x; 6.3939x over previous
//
#include <hip/hip_runtime.h>
#include <hip/hip_bf16.h>

// Persistent cooperative RNN kernel for MI355X (gfx950) — barrier-free
// epoch-tagged dataflow (round-0 proven structure + register-neutral opts).
// 256 WGs x 512 threads, 1 WG/CU (~152KB LDS). Each WG owns 4 hidden rows =>
// 16 gate rows of every 4H weight matrix. Cross-WG values are 8-byte
// (f32 value, u32 epoch) pairs via agent-scope 64-bit atomic stores, consumed
// by polling coherent (sc0 sc1) 16B loads. Small matvecs (cls/fut per decoder
// iter) use split-K partials reduced by dedicated WGs (2-hop) — the proven
// round-0 path. Register-resident cls/fut weights were tried in rounds 2-6
// and ALWAYS spill: this toolchain caps the kernel at 128 VGPRs regardless of
// __launch_bounds__ / amdgpu_waves_per_eu / thread count. Do not retry.
// Register-neutral refinements over round 0:
//  - enc_pre: encWhh@h(t) partial computed at R2 (1 reg); R1's encoder dot is
//    only 128 cols and R1 no longer polls h at all.
//  - merged h+c poll at R2 (one vmcnt(0) spin over both).
//  - x(t+1) prefetched into LDS at R3.
//  - reducer WGs stage dh BEFORE reduce_phase (partial-detect overlaps accA;
//    removes the reducers' laggard dh-row penalty on the next leg).
//  - explicit barrier after R2 closes the enc_score/R3-poll xs race.

typedef unsigned short u16t;
typedef unsigned int u32t;
typedef unsigned long long u64t;

#define TSTEPS 2045
#define NWG 256
#define NTHR 512
#define SPINCAP 8192

// d_ws float offsets (all pair arrays: 2 floats per element)
#define HENC  0        // [par][1024 pairs]  enc h
#define CENC  4096     // [par][1024 pairs]  enc c
#define DHX   8192     // [par][1024 pairs]  head dhx
#define DD1   12288    // [par][1024 pairs]  dec h1
#define DD2   16384    // [par][1024 pairs]  dec h2
#define SFF   20480    // [par][3 ph][128 pairs]   ds(0..63)|f(64..127)
#define PARTF 22016    // [par][3 ph][128 out][256 wg pairs]

struct Params {
  const void *X, *eWih, *eWhh, *ebih, *ebhh, *dWih, *dWhh, *dbih, *dbhh,
             *hxW, *hxb, *cxW, *cxb, *fusW, *fusb_g, *futW, *futb_g, *clsW, *clsb_g;
  float* ws;
  void* out;
};

struct SharedMem {
  alignas(16) float encW[16 * 1152];   // [row][Wih(128)|Whh(1024)] f32, 73728B
  alignas(16) u16t  decW[16 * 2048];   // [row][Wih(1024)|Whh(1024)] bf16, 65536B
  alignas(16) float xs[2048];          // staged vectors for dots
  alignas(16) float xsf[128];          // R1 fusion input [x(64)|fut(64)]
  float cls_sl[256], fut_sl[256];      // [o][j]: this WG's 4 columns
  float clsb[64], futb[64], fut_acc[64], dsbuf[64], fv3[64], xnext[64];
  float bias_e[16], bias_d[16], g16[16];
  float h4[4], dcx_s[4], encc[4], hxb4[4], cxb4[4];
  int bail;
  int badcnt;
};

__device__ __forceinline__ float bfu(u16t u){
  union { u32t i; float f; } v; v.i = ((u32t)u) << 16; return v.f;
}
__device__ __forceinline__ u32t fbits(float f){
  union { float f; u32t u; } c; c.f = f; return c.u;
}
__device__ __forceinline__ u16t bf16bits(float v){
  __hip_bfloat16 b = __float2bfloat16(v);
  union { __hip_bfloat16 b; u16t u; } c; c.b = b; return c.u;
}
template<bool F32>
__device__ __forceinline__ float ldE(const void* p, int i){
  if (F32) return ((const float*)p)[i];
  return bfu(((const u16t*)p)[i]);
}
template<bool F32>
__device__ __forceinline__ u16t ldB(const void* p, int i){
  if (F32) return bf16bits(((const float*)p)[i]);
  return ((const u16t*)p)[i];
}
template<bool F32>
__device__ __forceinline__ void stO(void* p, int i, float v){
  if (F32) ((float*)p)[i] = v;
  else     ((u16t*)p)[i] = bf16bits(v);
}
__device__ __forceinline__ float sigm(float x){ return 1.f / (1.f + __expf(-x)); }
__device__ __forceinline__ float tanhx(float x){
  float e = __expf(-2.f * fabsf(x));
  float t = (1.f - e) / (1.f + e);
  return copysignf(t, x);
}
// Tagged-pair store: (value, epoch) as one 64-bit agent-scope atomic.
__device__ __forceinline__ void stp(float* rowbase, int idx, float v, u32t ep){
  u64t u = (u64t)fbits(v) | ((u64t)ep << 32);
  __hip_atomic_store((u64t*)rowbase + idx, u,
                     __ATOMIC_RELAXED, __HIP_MEMORY_SCOPE_AGENT);
}
// Coherent 16B load (device coherence point).
__device__ __forceinline__ float4 ld4c(const float* p){
  float4 r;
  asm volatile("global_load_dwordx4 %0, %1, off sc0 sc1\n\t"
               "s_waitcnt vmcnt(0)"
               : "=&v"(r) : "v"(p) : "memory");
  return r;
}
// Two coherent 16B loads, single wait.
__device__ __forceinline__ void ld4c2(const float* p0, const float* p1,
                                      float4& a, float4& b){
  asm volatile(
    "global_load_dwordx4 %0, %2, off sc0 sc1\n\t"
    "global_load_dwordx4 %1, %3, off sc0 sc1\n\t"
    "s_waitcnt vmcnt(0)"
    : "=&v"(a), "=&v"(b)
    : "v"(p0), "v"(p1)
    : "memory");
}
// 4 coherent 16B loads, single wait.
__device__ __forceinline__ void ld4c4(const float* p0, const float* p1,
                                      const float* p2, const float* p3,
                                      float4& r0, float4& r1, float4& r2, float4& r3){
  asm volatile(
    "global_load_dwordx4 %0, %4, off sc0 sc1\n\t"
    "global_load_dwordx4 %1, %5, off sc0 sc1\n\t"
    "global_load_dwordx4 %2, %6, off sc0 sc1\n\t"
    "global_load_dwordx4 %3, %7, off sc0 sc1\n\t"
    "s_waitcnt vmcnt(0)"
    : "=&v"(r0), "=&v"(r1), "=&v"(r2), "=&v"(r3)
    : "v"(p0), "v"(p1), "v"(p2), "v"(p3)
    : "memory");
}
// Poll one quad (2 tagged pairs) until both tags == ep.
__device__ __forceinline__ float2 poll2(const float* q, u32t ep, int* bail){
  float4 r; int sp = 0;
  for (;;){
    r = ld4c(q);
    if (fbits(r.y) == ep && fbits(r.w) == ep) break;
    if (*bail) break;
    if (++sp > SPINCAP){ *bail = 1; break; }
  }
  return float2{r.x, r.z};
}

// Half-wave (32 lanes) dot of GLOBAL weight row with f32 x (LDS).
template<bool F32>
__device__ __forceinline__ float hw_dot(const void* wbase, long off,
                                        const float* __restrict__ x,
                                        int K, int lane){
  float acc = 0.f;
  if (F32){
    const float* w = (const float*)wbase + off;
    for (int c = lane * 4; c < K; c += 128){
      float4 wv = *(const float4*)(w + c);
      float4 xv = *(const float4*)(x + c);
      acc = fmaf(wv.x, xv.x, acc); acc = fmaf(wv.y, xv.y, acc);
      acc = fmaf(wv.z, xv.z, acc); acc = fmaf(wv.w, xv.w, acc);
    }
  } else {
    const u16t* w = (const u16t*)wbase + off;
    for (int c = lane * 4; c < K; c += 128){
      ushort4 wv = *(const ushort4*)(w + c);
      float4  xv = *(const float4*)(x + c);
      acc = fmaf(bfu(wv.x), xv.x, acc); acc = fmaf(bfu(wv.y), xv.y, acc);
      acc = fmaf(bfu(wv.z), xv.z, acc); acc = fmaf(bfu(wv.w), xv.w, acc);
    }
  }
  #pragma unroll
  for (int o = 16; o; o >>= 1) acc += __shfl_xor(acc, o, 64);
  return acc;
}

// Un-reduced per-lane dot partial (half-wave, stride 128); reduce with wred.
__device__ __forceinline__ float dotnr_f32(const float* __restrict__ w,
                                           const float* __restrict__ x,
                                           int K, int lane){
  float acc = 0.f;
  for (int c = lane * 4; c < K; c += 128){
    float4 wv = *(const float4*)(w + c);
    float4 xv = *(const float4*)(x + c);
    acc = fmaf(wv.x, xv.x, acc); acc = fmaf(wv.y, xv.y, acc);
    acc = fmaf(wv.z, xv.z, acc); acc = fmaf(wv.w, xv.w, acc);
  }
  return acc;
}
__device__ __forceinline__ float wred(float a){
  #pragma unroll
  for (int o = 16; o; o >>= 1) a += __shfl_xor(a, o, 64);
  return a;
}

__device__ __forceinline__ float lds_dot_bf16(const u16t* __restrict__ w,
                                              const float* __restrict__ x,
                                              int K, int lane){
  float acc = 0.f;
  for (int c = lane * 8; c < K; c += 256){
    uint4  wv = *(const uint4*)(w + c);
    float4 x0 = *(const float4*)(x + c);
    float4 x1 = *(const float4*)(x + c + 4);
    acc = fmaf(bfu((u16t)(wv.x & 0xffff)), x0.x, acc);
    acc = fmaf(bfu((u16t)(wv.x >> 16)),    x0.y, acc);
    acc = fmaf(bfu((u16t)(wv.y & 0xffff)), x0.z, acc);
    acc = fmaf(bfu((u16t)(wv.y >> 16)),    x0.w, acc);
    acc = fmaf(bfu((u16t)(wv.z & 0xffff)), x1.x, acc);
    acc = fmaf(bfu((u16t)(wv.z >> 16)),    x1.y, acc);
    acc = fmaf(bfu((u16t)(wv.w & 0xffff)), x1.z, acc);
    acc = fmaf(bfu((u16t)(wv.w >> 16)),    x1.w, acc);
  }
  #pragma unroll
  for (int o = 16; o; o >>= 1) acc += __shfl_xor(acc, o, 64);
  return acc;
}

// Dedicated-WG reduction of one output's 256 split-K partials.
template<bool F32>
__device__ __forceinline__ void reduce_phase(float* ws, int ph, int par, u32t ep,
                                             int t, SharedMem& S, void* out,
                                             int w, int hw, int lane){
  const int o = (w & 7) * 16 + hw;
  const float* row = ws + PARTF + (size_t)((par * 3 + ph) * 128 + o) * 512;
  const float* q = row + lane * 16;
  float4 r0, r1, r2, r3; int sp = 0;
  for (;;){
    ld4c4(q, q + 4, q + 8, q + 12, r0, r1, r2, r3);
    if (fbits(r0.y) == ep && fbits(r0.w) == ep && fbits(r1.y) == ep &&
        fbits(r1.w) == ep && fbits(r2.y) == ep && fbits(r2.w) == ep &&
        fbits(r3.y) == ep && fbits(r3.w) == ep) break;
    if (S.bail) break;
    if (++sp > SPINCAP){ S.bail = 1; break; }
  }
  float s = r0.x + r0.z + r1.x + r1.z + r2.x + r2.z + r3.x + r3.z;
  #pragma unroll
  for (int m = 16; m; m >>= 1) s += __shfl_xor(s, m, 64);
  if (lane == 0){
    float* sf = ws + SFF + (par * 3 + ph) * 256;
    if (o < 64){
      float v = s + S.clsb[o];
      stO<F32>(out, TSTEPS * 64 + (t * 3 + ph) * 64 + o, v);
      if (ph < 2) stp(sf, o, v, ep);
    } else {
      float v = fmaxf(s + S.futb[o - 64], 0.f);
      stp(sf, o, v, ep);
    }
  }
}

template<bool F32>
__device__ void run(const Params& p, SharedMem& S){
  const int tid  = threadIdx.x;
  const int w    = blockIdx.x;
  const int hw   = tid >> 5;            // half-wave 0..15 -> one gate row each
  const int lane = tid & 31;
  const long grow = (long)((hw >> 2) * 1024 + 4 * w + (hw & 3));  // gate row
  float* ws = p.ws;

  // ---------- startup: stage per-WG weights into LDS ----------
  {
    float* er = S.encW + hw * 1152;
    for (int c = lane; c < 128; c += 32)  er[c]       = ldE<F32>(p.eWih, (int)(grow * 128 + c));
    for (int c = lane; c < 1024; c += 32) er[128 + c] = ldE<F32>(p.eWhh, (int)(grow * 1024 + c));
    u16t* dr = S.decW + hw * 2048;
    for (int c = lane; c < 1024; c += 32){
      dr[c]        = ldB<F32>(p.dWih, (int)(grow * 1024 + c));
      dr[1024 + c] = ldB<F32>(p.dWhh, (int)(grow * 1024 + c));
    }
  }
  // fus_W rows for this thread's two h outputs -> registers (proven: no spill)
  u32t fw[64];
  float fusb0, fusb1;
  {
    int h0 = 2 * tid, h1 = 2 * tid + 1;
    #pragma unroll
    for (int o = 0; o < 64; ++o){
      u16t lo = ldB<F32>(p.fusW, h0 * 64 + o);
      u16t hi = ldB<F32>(p.fusW, h1 * 64 + o);
      fw[o] = ((u32t)hi << 16) | lo;
    }
    fusb0 = ldE<F32>(p.fusb_g, h0);
    fusb1 = ldE<F32>(p.fusb_g, h1);
  }
  if (tid < 256){
    int o = tid >> 2, j = tid & 3;
    S.cls_sl[tid] = ldE<F32>(p.clsW, o * 1024 + 4 * w + j);
    S.fut_sl[tid] = ldE<F32>(p.futW, o * 1024 + 4 * w + j);
  }
  if (tid < 64){
    S.clsb[tid] = ldE<F32>(p.clsb_g, tid);
    S.futb[tid] = ldE<F32>(p.futb_g, tid);
    S.fut_acc[tid] = 0.f;
  }
  if (tid < 16){
    int gr = (tid >> 2) * 1024 + 4 * w + (tid & 3);
    S.bias_e[tid] = ldE<F32>(p.ebih, gr) + ldE<F32>(p.ebhh, gr);
    S.bias_d[tid] = ldE<F32>(p.dbih, gr) + ldE<F32>(p.dbhh, gr);
  }
  if (tid < 4){
    S.hxb4[tid] = ldE<F32>(p.hxb, 4 * w + tid);
    S.cxb4[tid] = ldE<F32>(p.cxb, 4 * w + tid);
    S.encc[tid] = 0.f;
  }
  float enc_pre = 0.f;   // per-lane partial of encWhh @ h(t-1); h(-1)=0
  __syncthreads();

  for (int t = 0; t < TSTEPS; ++t){
    const int  par  = t & 1;
    const int  ppar = par ^ 1;
    const u32t ep   = (u32t)(t + 1);
    const u32t epv  = (u32t)t;            // tag of previous step's values

    // ============ R1: encoder gates (h part carried in enc_pre) ============
    if (t > 0 && tid < 32){               // f3 pairs: SF[ppar][ph2] quads 32..63
      const float* base = ws + SFF + (ppar * 3 + 2) * 256;
      float2 v = poll2(base + (32 + tid) * 4, epv, &S.bail);
      S.fv3[2 * tid] = v.x; S.fv3[2 * tid + 1] = v.y;
    }
    __syncthreads();
    if (tid < 64){
      S.xsf[tid] = (t == 0) ? ldE<F32>(p.X, tid) : S.xnext[tid];
      float fv = (t > 0) ? (S.fut_acc[tid] + S.fv3[tid]) * (1.f / 3.f) : 0.f;
      S.xsf[64 + tid] = fv;
      S.fut_acc[tid] = 0.f;
    }
    __syncthreads();
    {
      float a = wred(enc_pre + dotnr_f32(S.encW + hw * 1152, S.xsf, 128, lane))
              + S.bias_e[hw];
      if (lane == 0) S.g16[hw] = a;
    }
    __syncthreads();
    if (tid < 4){
      float gi = sigm(S.g16[tid]), gf = sigm(S.g16[4 + tid]),
            gg = tanhx(S.g16[8 + tid]), go = sigm(S.g16[12 + tid]);
      float c = gf * S.encc[tid] + gi * gg;
      float h = go * tanhx(c);
      S.encc[tid] = c;
      stp(ws + HENC + par * 2048, 4 * w + tid, h, ep);
      stp(ws + CENC + par * 2048, 4 * w + tid, c, ep);
    }

    // ============ R2: merged h+c poll; heads dhx/dcx; enc_score; enc_pre ====
    {
      const float* ph_ = ws + HENC + par * 2048 + tid * 4;
      const float* pc_ = ws + CENC + par * 2048 + tid * 4;
      float4 a, b; int sp = 0;
      for (;;){
        ld4c2(ph_, pc_, a, b);
        if (fbits(a.y) == ep && fbits(a.w) == ep &&
            fbits(b.y) == ep && fbits(b.w) == ep) break;
        if (S.bail) break;
        if (++sp > SPINCAP){ S.bail = 1; break; }
      }
      S.xs[2 * tid] = a.x;        S.xs[2 * tid + 1] = a.z;
      S.xs[1024 + 2 * tid] = b.x; S.xs[1025 + 2 * tid] = b.z;
    }
    __syncthreads();
    if (hw < 4){
      float d = fmaxf(hw_dot<F32>(p.hxW, (long)(4 * w + hw) * 1024, S.xs, 1024, lane)
                      + S.hxb4[hw], 0.f);
      if (lane == 0) stp(ws + DHX + par * 2048, 4 * w + hw, d, ep);
    } else if (hw < 8){
      int j = hw - 4;
      float d = fmaxf(hw_dot<F32>(p.cxW, (long)(4 * w + j) * 1024, S.xs + 1024, 1024, lane)
                      + S.cxb4[j], 0.f);
      if (lane == 0) S.dcx_s[j] = d;   // decoder c, reused by all 3 iters (ref bug)
    } else if (w >= 8 && w < 16){      // enc_score: 8 WGs x 8 half-waves
      int r = (w - 8) * 8 + (hw - 8);
      float s = hw_dot<F32>(p.clsW, (long)r * 1024, S.xs, 1024, lane) + S.clsb[r];
      if (lane == 0) stO<F32>(p.out, t * 64 + r, s);
    }
    // next step's encoder Whh@h partial, in R2's shadow (after DHX stp)
    enc_pre = dotnr_f32(S.encW + hw * 1152 + 128, S.xs, 1024, lane);
    __syncthreads();   // protect xs readers (enc_score/dcx) from R3 overwrite

    // ============ R3: decoder iter 1 (fusion_in = 0) ============
    {
      float2 v = poll2(ws + DHX + par * 2048 + tid * 4, ep, &S.bail);
      S.xs[2 * tid] = v.x; S.xs[2 * tid + 1] = v.y;
    }
    __syncthreads();
    {
      float a = lds_dot_bf16(S.decW + hw * 2048 + 1024, S.xs, 1024, lane) + S.bias_d[hw];
      if (lane == 0) S.g16[hw] = a;
    }
    __syncthreads();
    if (tid < 4){
      float gi = sigm(S.g16[tid]), gf = sigm(S.g16[4 + tid]),
            gg = tanhx(S.g16[8 + tid]), go = sigm(S.g16[12 + tid]);
      float c = gf * S.dcx_s[tid] + gi * gg;
      float h = go * tanhx(c);
      S.h4[tid] = h;
      stp(ws + DD1 + par * 2048, 4 * w + tid, h, ep);
    }
    __syncthreads();
    if (tid < 64){                    // split-K partials (cls, fut) @ dh1 -> ph0
      float sv = 0.f, fv = 0.f;
      #pragma unroll
      for (int j = 0; j < 4; ++j){
        sv = fmaf(S.cls_sl[tid * 4 + j], S.h4[j], sv);
        fv = fmaf(S.fut_sl[tid * 4 + j], S.h4[j], fv);
      }
      float* base = ws + PARTF + (size_t)((par * 3 + 0) * 128) * 512;
      stp(base + (size_t)tid * 512,        w, sv, ep);
      stp(base + (size_t)(64 + tid) * 512, w, fv, ep);
      S.xnext[tid] = ldE<F32>(p.X, (t + 1) * 64 + tid);   // prefetch x(t+1)
    }

    // ============ R4/R5: decoder iters 2,3 ============
    for (int di = 2; di <= 3; ++di){
      const int ph = di - 2;               // partials produced in prev round
      // stage dh_{di-1} -> xs[1024:2048]
      {
        const float* dbuf = ws + (di == 2 ? DD1 : DD2) + par * 2048;
        float2 v = poll2(dbuf + tid * 4, ep, &S.bail);
        S.xs[1024 + 2 * tid] = v.x; S.xs[1025 + 2 * tid] = v.y;
      }
      __syncthreads();
      float accA = lds_dot_bf16(S.decW + hw * 2048 + 1024, S.xs + 1024, 1024, lane);
      // dedicated reducers AFTER staging+accA: partial-detect overlaps compute,
      // and the reducer WG's own dh rows are no longer a leg late.
      if (w >= 16 + ph * 8 && w < 24 + ph * 8)
        reduce_phase<F32>(ws, ph, par, ep, t, S, p.out, w, hw, lane);
      // poll ds/f broadcast (produced by reducers)
      if (tid < 64){
        const float* sf = ws + SFF + (par * 3 + ph) * 256;
        float2 v = poll2(sf + tid * 4, ep, &S.bail);
        if (tid < 32){ S.dsbuf[2 * tid] = v.x; S.dsbuf[2 * tid + 1] = v.y; }
        else { S.fv3[2 * (tid - 32)] = v.x; S.fv3[2 * (tid - 32) + 1] = v.y; }
      }
      __syncthreads();
      if (tid < 64) S.fut_acc[tid] += S.fv3[tid];
      {   // fusion_in = relu(fus_W @ ds + fus_b), per-thread 2 rows from VGPRs
        float a0 = fusb0, a1 = fusb1;
        #pragma unroll
        for (int o = 0; o < 64; ++o){
          float d = S.dsbuf[o];
          a0 = fmaf(bfu((u16t)(fw[o] & 0xffff)), d, a0);
          a1 = fmaf(bfu((u16t)(fw[o] >> 16)),    d, a1);
        }
        S.xs[2 * tid]     = fmaxf(a0, 0.f);
        S.xs[2 * tid + 1] = fmaxf(a1, 0.f);
      }
      __syncthreads();
      float accB = lds_dot_bf16(S.decW + hw * 2048, S.xs, 1024, lane);
      {
        float a = accA + accB + S.bias_d[hw];
        if (lane == 0) S.g16[hw] = a;
      }
      __syncthreads();
      if (tid < 4){
        float gi = sigm(S.g16[tid]), gf = sigm(S.g16[4 + tid]),
              gg = tanhx(S.g16[8 + tid]), go = sigm(S.g16[12 + tid]);
        float c = gf * S.dcx_s[tid] + gi * gg;
        float h = go * tanhx(c);
        S.h4[tid] = h;
        if (di == 2) stp(ws + DD2 + par * 2048, 4 * w + tid, h, ep);
      }
      __syncthreads();
      if (tid < 64){                    // partials @ dh_di -> ph(di-1)
        float sv = 0.f, fv = 0.f;
        #pragma unroll
        for (int j = 0; j < 4; ++j){
          sv = fmaf(S.cls_sl[tid * 4 + j], S.h4[j], sv);
          fv = fmaf(S.fut_sl[tid * 4 + j], S.h4[j], fv);
        }
        float* base = ws + PARTF + (size_t)((par * 3 + di - 1) * 128) * 512;
        stp(base + (size_t)tid * 512,        w, sv, ep);
        stp(base + (size_t)(64 + tid) * 512, w, fv, ep);
      }
    }
    // ph2 reducers: produce ds3 (-> out) and f3 (-> next step's R1)
    if (w >= 32 && w < 40)
      reduce_phase<F32>(ws, 2, par, ep, t, S, p.out, w, hw, lane);
  }
}

__global__ __launch_bounds__(NTHR, 2)
void trn_persist(Params p){
  __shared__ SharedMem S;
  // ---- runtime input-dtype detection from X's bit patterns ----
  if (threadIdx.x == 0){ S.bail = 0; S.badcnt = 0; }
  __syncthreads();
  if (threadIdx.x < 256){
    u16t u = ((const u16t*)p.X)[threadIdx.x];
    int e = (u >> 7) & 0xff;
    if (e == 0 || e >= 141) atomicAdd(&S.badcnt, 1);
  }
  __syncthreads();
  if (S.badcnt >= 3) run<true>(p, S);
  else               run<false>(p, S);
}

extern "C" void kernel_launch(void* const* d_in, const int* in_sizes, int n_in,
                              void* d_out, int out_size, void* d_ws, size_t ws_size,
                              hipStream_t stream){
  Params P;
  P.X      = d_in[0];
  P.eWih   = d_in[1];
  P.eWhh   = d_in[2];
  P.ebih   = d_in[3];
  P.ebhh   = d_in[4];
  P.dWih   = d_in[5];
  P.dWhh   = d_in[6];
  P.dbih   = d_in[7];
  P.dbhh   = d_in[8];
  P.hxW    = d_in[9];
  P.hxb    = d_in[10];
  P.cxW    = d_in[11];
  P.cxb    = d_in[12];
  P.fusW   = d_in[13];
  P.fusb_g = d_in[14];
  P.futW   = d_in[15];
  P.futb_g = d_in[16];
  P.clsW   = d_in[17];
  P.clsb_g = d_in[18];
  P.ws     = (float*)d_ws;
  P.out    = d_out;

  void* args[] = { &P };
  hipLaunchCooperativeKernel((void*)trn_persist, dim3(NWG), dim3(NTHR),
                             args, 0, stream);
}

// Round 8
// 51039.993 us; speedup vs baseline: 7.1867x; 1.1240x over previous
//
#include <hip/hip_runtime.h>
#include <hip/hip_bf16.h>

// Persistent cooperative RNN kernel for MI355X (gfx950) — barrier-free
// epoch-tagged dataflow. 256 WGs x 512 threads, 1 WG/CU (~150KB LDS).
// Each WG owns 4 hidden rows => 16 gate rows of every 4H weight matrix.
// Cross-WG values are 8-byte (f32 value, u32 epoch) pairs via agent-scope
// 64-bit atomic stores, consumed by polling coherent (sc0 sc1) 16B loads.
// ROUND-8 CHANGES (theory: spin-loop L3 traffic inflates every leg):
//  1. All spin loops back off with s_sleep after the first misses — cuts the
//     ~4TB/s of continuous coherent poll traffic several-fold.
//  2. Split-K partials are GONE. The ds/f producer WGs (w16-39) compute their
//     16 outputs directly from the dh_i broadcast they already poll, via
//     hw_dot on global clsW/futW rows (L2-hot, same pattern as enc_score).
//     This removes 786KB/step of 2KB-strided tagged stores (whose write-back
//     amplification was the entire 6.4GB WRITE_SIZE) and the 64B/lane
//     straggler-scan detect loop. dh3 gets a DD3 broadcast (4 pairs/WG).
// Register notes (rounds 2-6): this toolchain caps the kernel at 128 VGPRs
// regardless of attributes; register-resident cls/fut weights always spill.
// fw[64] (fusW rows) fits without spill — proven in round 0/7.

typedef unsigned short u16t;
typedef unsigned int u32t;
typedef unsigned long long u64t;

#define TSTEPS 2045
#define NWG 256
#define NTHR 512
#define SPINCAP 8192

// d_ws float offsets (all pair arrays: 2 floats per element)
#define HENC  0        // [par][1024 pairs]  enc h
#define CENC  4096     // [par][1024 pairs]  enc c
#define DHX   8192     // [par][1024 pairs]  head dhx
#define DD1   12288    // [par][1024 pairs]  dec h1
#define DD2   16384    // [par][1024 pairs]  dec h2
#define DD3   20480    // [par][1024 pairs]  dec h3
#define SFF   24576    // [par][3 ph][128 pairs]   ds(0..63)|f(64..127)

struct Params {
  const void *X, *eWih, *eWhh, *ebih, *ebhh, *dWih, *dWhh, *dbih, *dbhh,
             *hxW, *hxb, *cxW, *cxb, *fusW, *fusb_g, *futW, *futb_g, *clsW, *clsb_g;
  float* ws;
  void* out;
};

struct SharedMem {
  alignas(16) float encW[16 * 1152];   // [row][Wih(128)|Whh(1024)] f32, 73728B
  alignas(16) u16t  decW[16 * 2048];   // [row][Wih(1024)|Whh(1024)] bf16, 65536B
  alignas(16) float xs[2048];          // staged vectors for dots
  alignas(16) float xsf[128];          // R1 fusion input [x(64)|fut(64)]
  float clsb[64], futb[64], fut_acc[64], dsbuf[64], fv3[64], xnext[64];
  float bias_e[16], bias_d[16], g16[16];
  float dcx_s[4], encc[4], hxb4[4], cxb4[4];
  int bail;
  int badcnt;
};

__device__ __forceinline__ float bfu(u16t u){
  union { u32t i; float f; } v; v.i = ((u32t)u) << 16; return v.f;
}
__device__ __forceinline__ u32t fbits(float f){
  union { float f; u32t u; } c; c.f = f; return c.u;
}
__device__ __forceinline__ u16t bf16bits(float v){
  __hip_bfloat16 b = __float2bfloat16(v);
  union { __hip_bfloat16 b; u16t u; } c; c.b = b; return c.u;
}
template<bool F32>
__device__ __forceinline__ float ldE(const void* p, int i){
  if (F32) return ((const float*)p)[i];
  return bfu(((const u16t*)p)[i]);
}
template<bool F32>
__device__ __forceinline__ u16t ldB(const void* p, int i){
  if (F32) return bf16bits(((const float*)p)[i]);
  return ((const u16t*)p)[i];
}
template<bool F32>
__device__ __forceinline__ void stO(void* p, int i, float v){
  if (F32) ((float*)p)[i] = v;
  else     ((u16t*)p)[i] = bf16bits(v);
}
__device__ __forceinline__ float sigm(float x){ return 1.f / (1.f + __expf(-x)); }
__device__ __forceinline__ float tanhx(float x){
  float e = __expf(-2.f * fabsf(x));
  float t = (1.f - e) / (1.f + e);
  return copysignf(t, x);
}
// Escalating backoff for spin loops: free for the first couple of probes,
// then sleep to cut coherent-load traffic while waiting.
__device__ __forceinline__ void backoff(int sp){
  if (sp > 8)      __builtin_amdgcn_s_sleep(8);   // ~213ns
  else if (sp > 2) __builtin_amdgcn_s_sleep(2);   // ~53ns
}
// Tagged-pair store: (value, epoch) as one 64-bit agent-scope atomic.
__device__ __forceinline__ void stp(float* rowbase, int idx, float v, u32t ep){
  u64t u = (u64t)fbits(v) | ((u64t)ep << 32);
  __hip_atomic_store((u64t*)rowbase + idx, u,
                     __ATOMIC_RELAXED, __HIP_MEMORY_SCOPE_AGENT);
}
// Coherent 16B load (device coherence point).
__device__ __forceinline__ float4 ld4c(const float* p){
  float4 r;
  asm volatile("global_load_dwordx4 %0, %1, off sc0 sc1\n\t"
               "s_waitcnt vmcnt(0)"
               : "=&v"(r) : "v"(p) : "memory");
  return r;
}
// Two coherent 16B loads, single wait.
__device__ __forceinline__ void ld4c2(const float* p0, const float* p1,
                                      float4& a, float4& b){
  asm volatile(
    "global_load_dwordx4 %0, %2, off sc0 sc1\n\t"
    "global_load_dwordx4 %1, %3, off sc0 sc1\n\t"
    "s_waitcnt vmcnt(0)"
    : "=&v"(a), "=&v"(b)
    : "v"(p0), "v"(p1)
    : "memory");
}
// Poll one quad (2 tagged pairs) until both tags == ep.
__device__ __forceinline__ float2 poll2(const float* q, u32t ep, int* bail){
  float4 r; int sp = 0;
  for (;;){
    r = ld4c(q);
    if (fbits(r.y) == ep && fbits(r.w) == ep) break;
    if (*bail) break;
    if (++sp > SPINCAP){ *bail = 1; break; }
    backoff(sp);
  }
  return float2{r.x, r.z};
}

// Half-wave (32 lanes) dot of GLOBAL weight row with f32 x (LDS).
template<bool F32>
__device__ __forceinline__ float hw_dot(const void* wbase, long off,
                                        const float* __restrict__ x,
                                        int K, int lane){
  float acc = 0.f;
  if (F32){
    const float* w = (const float*)wbase + off;
    for (int c = lane * 4; c < K; c += 128){
      float4 wv = *(const float4*)(w + c);
      float4 xv = *(const float4*)(x + c);
      acc = fmaf(wv.x, xv.x, acc); acc = fmaf(wv.y, xv.y, acc);
      acc = fmaf(wv.z, xv.z, acc); acc = fmaf(wv.w, xv.w, acc);
    }
  } else {
    const u16t* w = (const u16t*)wbase + off;
    for (int c = lane * 4; c < K; c += 128){
      ushort4 wv = *(const ushort4*)(w + c);
      float4  xv = *(const float4*)(x + c);
      acc = fmaf(bfu(wv.x), xv.x, acc); acc = fmaf(bfu(wv.y), xv.y, acc);
      acc = fmaf(bfu(wv.z), xv.z, acc); acc = fmaf(bfu(wv.w), xv.w, acc);
    }
  }
  #pragma unroll
  for (int o = 16; o; o >>= 1) acc += __shfl_xor(acc, o, 64);
  return acc;
}

// Un-reduced per-lane dot partial (half-wave, stride 128); reduce with wred.
__device__ __forceinline__ float dotnr_f32(const float* __restrict__ w,
                                           const float* __restrict__ x,
                                           int K, int lane){
  float acc = 0.f;
  for (int c = lane * 4; c < K; c += 128){
    float4 wv = *(const float4*)(w + c);
    float4 xv = *(const float4*)(x + c);
    acc = fmaf(wv.x, xv.x, acc); acc = fmaf(wv.y, xv.y, acc);
    acc = fmaf(wv.z, xv.z, acc); acc = fmaf(wv.w, xv.w, acc);
  }
  return acc;
}
__device__ __forceinline__ float wred(float a){
  #pragma unroll
  for (int o = 16; o; o >>= 1) a += __shfl_xor(a, o, 64);
  return a;
}

__device__ __forceinline__ float lds_dot_bf16(const u16t* __restrict__ w,
                                              const float* __restrict__ x,
                                              int K, int lane){
  float acc = 0.f;
  for (int c = lane * 8; c < K; c += 256){
    uint4  wv = *(const uint4*)(w + c);
    float4 x0 = *(const float4*)(x + c);
    float4 x1 = *(const float4*)(x + c + 4);
    acc = fmaf(bfu((u16t)(wv.x & 0xffff)), x0.x, acc);
    acc = fmaf(bfu((u16t)(wv.x >> 16)),    x0.y, acc);
    acc = fmaf(bfu((u16t)(wv.y & 0xffff)), x0.z, acc);
    acc = fmaf(bfu((u16t)(wv.y >> 16)),    x0.w, acc);
    acc = fmaf(bfu((u16t)(wv.z & 0xffff)), x1.x, acc);
    acc = fmaf(bfu((u16t)(wv.z >> 16)),    x1.y, acc);
    acc = fmaf(bfu((u16t)(wv.w & 0xffff)), x1.z, acc);
    acc = fmaf(bfu((u16t)(wv.w >> 16)),    x1.w, acc);
  }
  #pragma unroll
  for (int o = 16; o; o >>= 1) acc += __shfl_xor(acc, o, 64);
  return acc;
}

// Direct ds/f production: 16 outputs o=(w&7)*16+hw from the dh broadcast
// already staged in LDS (xs[1024:2048]), weights from global (L2-hot).
// o<64: ds -> out (+ SFF broadcast if ph<2). o>=64: f -> SFF broadcast.
template<bool F32>
__device__ __forceinline__ void produce_sf(const Params& p, float* ws,
                                           SharedMem& S, int ph, int par,
                                           u32t ep, int t, int w, int hw,
                                           int lane){
  const int o = (w & 7) * 16 + hw;
  float* sf = ws + SFF + (par * 3 + ph) * 256;
  if (o < 64){
    float s = hw_dot<F32>(p.clsW, (long)o * 1024, S.xs + 1024, 1024, lane)
            + S.clsb[o];
    if (lane == 0){
      stO<F32>(p.out, TSTEPS * 64 + (t * 3 + ph) * 64 + o, s);
      if (ph < 2) stp(sf, o, s, ep);
    }
  } else {
    float s = fmaxf(hw_dot<F32>(p.futW, (long)(o - 64) * 1024, S.xs + 1024, 1024, lane)
                    + S.futb[o - 64], 0.f);
    if (lane == 0) stp(sf, o, s, ep);
  }
}

template<bool F32>
__device__ void run(const Params& p, SharedMem& S){
  const int tid  = threadIdx.x;
  const int w    = blockIdx.x;
  const int hw   = tid >> 5;            // half-wave 0..15 -> one gate row each
  const int lane = tid & 31;
  const long grow = (long)((hw >> 2) * 1024 + 4 * w + (hw & 3));  // gate row
  float* ws = p.ws;

  // ---------- startup: stage per-WG weights into LDS ----------
  {
    float* er = S.encW + hw * 1152;
    for (int c = lane; c < 128; c += 32)  er[c]       = ldE<F32>(p.eWih, (int)(grow * 128 + c));
    for (int c = lane; c < 1024; c += 32) er[128 + c] = ldE<F32>(p.eWhh, (int)(grow * 1024 + c));
    u16t* dr = S.decW + hw * 2048;
    for (int c = lane; c < 1024; c += 32){
      dr[c]        = ldB<F32>(p.dWih, (int)(grow * 1024 + c));
      dr[1024 + c] = ldB<F32>(p.dWhh, (int)(grow * 1024 + c));
    }
  }
  // fus_W rows for this thread's two h outputs -> registers (proven: no spill)
  u32t fw[64];
  float fusb0, fusb1;
  {
    int h0 = 2 * tid, h1 = 2 * tid + 1;
    #pragma unroll
    for (int o = 0; o < 64; ++o){
      u16t lo = ldB<F32>(p.fusW, h0 * 64 + o);
      u16t hi = ldB<F32>(p.fusW, h1 * 64 + o);
      fw[o] = ((u32t)hi << 16) | lo;
    }
    fusb0 = ldE<F32>(p.fusb_g, h0);
    fusb1 = ldE<F32>(p.fusb_g, h1);
  }
  if (tid < 64){
    S.clsb[tid] = ldE<F32>(p.clsb_g, tid);
    S.futb[tid] = ldE<F32>(p.futb_g, tid);
    S.fut_acc[tid] = 0.f;
  }
  if (tid < 16){
    int gr = (tid >> 2) * 1024 + 4 * w + (tid & 3);
    S.bias_e[tid] = ldE<F32>(p.ebih, gr) + ldE<F32>(p.ebhh, gr);
    S.bias_d[tid] = ldE<F32>(p.dbih, gr) + ldE<F32>(p.dbhh, gr);
  }
  if (tid < 4){
    S.hxb4[tid] = ldE<F32>(p.hxb, 4 * w + tid);
    S.cxb4[tid] = ldE<F32>(p.cxb, 4 * w + tid);
    S.encc[tid] = 0.f;
  }
  float enc_pre = 0.f;   // per-lane partial of encWhh @ h(t-1); h(-1)=0
  __syncthreads();

  for (int t = 0; t < TSTEPS; ++t){
    const int  par  = t & 1;
    const int  ppar = par ^ 1;
    const u32t ep   = (u32t)(t + 1);
    const u32t epv  = (u32t)t;            // tag of previous step's values

    // ============ R1: encoder gates (h part carried in enc_pre) ============
    if (t > 0 && tid < 32){               // f3 pairs: SF[ppar][ph2] quads 32..63
      const float* base = ws + SFF + (ppar * 3 + 2) * 256;
      float2 v = poll2(base + (32 + tid) * 4, epv, &S.bail);
      S.fv3[2 * tid] = v.x; S.fv3[2 * tid + 1] = v.y;
    }
    __syncthreads();
    if (tid < 64){
      S.xsf[tid] = (t == 0) ? ldE<F32>(p.X, tid) : S.xnext[tid];
      float fv = (t > 0) ? (S.fut_acc[tid] + S.fv3[tid]) * (1.f / 3.f) : 0.f;
      S.xsf[64 + tid] = fv;
      S.fut_acc[tid] = 0.f;
    }
    __syncthreads();
    {
      float a = wred(enc_pre + dotnr_f32(S.encW + hw * 1152, S.xsf, 128, lane))
              + S.bias_e[hw];
      if (lane == 0) S.g16[hw] = a;
    }
    __syncthreads();
    if (tid < 4){
      float gi = sigm(S.g16[tid]), gf = sigm(S.g16[4 + tid]),
            gg = tanhx(S.g16[8 + tid]), go = sigm(S.g16[12 + tid]);
      float c = gf * S.encc[tid] + gi * gg;
      float h = go * tanhx(c);
      S.encc[tid] = c;
      stp(ws + HENC + par * 2048, 4 * w + tid, h, ep);
      stp(ws + CENC + par * 2048, 4 * w + tid, c, ep);
    }

    // ============ R2: merged h+c poll; heads dhx/dcx; enc_score; enc_pre ====
    {
      const float* ph_ = ws + HENC + par * 2048 + tid * 4;
      const float* pc_ = ws + CENC + par * 2048 + tid * 4;
      float4 a, b; int sp = 0;
      for (;;){
        ld4c2(ph_, pc_, a, b);
        if (fbits(a.y) == ep && fbits(a.w) == ep &&
            fbits(b.y) == ep && fbits(b.w) == ep) break;
        if (S.bail) break;
        if (++sp > SPINCAP){ S.bail = 1; break; }
        backoff(sp);
      }
      S.xs[2 * tid] = a.x;        S.xs[2 * tid + 1] = a.z;
      S.xs[1024 + 2 * tid] = b.x; S.xs[1025 + 2 * tid] = b.z;
    }
    __syncthreads();
    if (hw < 4){
      float d = fmaxf(hw_dot<F32>(p.hxW, (long)(4 * w + hw) * 1024, S.xs, 1024, lane)
                      + S.hxb4[hw], 0.f);
      if (lane == 0) stp(ws + DHX + par * 2048, 4 * w + hw, d, ep);
    } else if (hw < 8){
      int j = hw - 4;
      float d = fmaxf(hw_dot<F32>(p.cxW, (long)(4 * w + j) * 1024, S.xs + 1024, 1024, lane)
                      + S.cxb4[j], 0.f);
      if (lane == 0) S.dcx_s[j] = d;   // decoder c, reused by all 3 iters (ref bug)
    } else if (w >= 8 && w < 16){      // enc_score: 8 WGs x 8 half-waves
      int r = (w - 8) * 8 + (hw - 8);
      float s = hw_dot<F32>(p.clsW, (long)r * 1024, S.xs, 1024, lane) + S.clsb[r];
      if (lane == 0) stO<F32>(p.out, t * 64 + r, s);
    }
    // next step's encoder Whh@h partial, in R2's shadow (after DHX stp)
    enc_pre = dotnr_f32(S.encW + hw * 1152 + 128, S.xs, 1024, lane);
    __syncthreads();   // protect xs readers (enc_score/dcx) from R3 overwrite

    // ============ R3: decoder iter 1 (fusion_in = 0) ============
    {
      float2 v = poll2(ws + DHX + par * 2048 + tid * 4, ep, &S.bail);
      S.xs[2 * tid] = v.x; S.xs[2 * tid + 1] = v.y;
    }
    __syncthreads();
    {
      float a = lds_dot_bf16(S.decW + hw * 2048 + 1024, S.xs, 1024, lane) + S.bias_d[hw];
      if (lane == 0) S.g16[hw] = a;
    }
    __syncthreads();
    if (tid < 4){
      float gi = sigm(S.g16[tid]), gf = sigm(S.g16[4 + tid]),
            gg = tanhx(S.g16[8 + tid]), go = sigm(S.g16[12 + tid]);
      float c = gf * S.dcx_s[tid] + gi * gg;
      float h = go * tanhx(c);
      stp(ws + DD1 + par * 2048, 4 * w + tid, h, ep);
    }
    if (tid < 64)
      S.xnext[tid] = ldE<F32>(p.X, (t + 1) * 64 + tid);   // prefetch x(t+1)

    // ============ R4/R5: decoder iters 2,3 ============
    for (int di = 2; di <= 3; ++di){
      const int ph = di - 2;               // sf phase produced this round
      // stage dh_{di-1} -> xs[1024:2048]
      {
        const float* dbuf = ws + (di == 2 ? DD1 : DD2) + par * 2048;
        float2 v = poll2(dbuf + tid * 4, ep, &S.bail);
        S.xs[1024 + 2 * tid] = v.x; S.xs[1025 + 2 * tid] = v.y;
      }
      __syncthreads();
      // ds/f producers FIRST (critical path for everyone's fusion), from the
      // dh broadcast just staged — no partials, no scan-detect.
      if (w >= 16 + ph * 8 && w < 24 + ph * 8)
        produce_sf<F32>(p, ws, S, ph, par, ep, t, w, hw, lane);
      float accA = lds_dot_bf16(S.decW + hw * 2048 + 1024, S.xs + 1024, 1024, lane);
      // poll ds/f broadcast
      if (tid < 64){
        const float* sf = ws + SFF + (par * 3 + ph) * 256;
        float2 v = poll2(sf + tid * 4, ep, &S.bail);
        if (tid < 32){ S.dsbuf[2 * tid] = v.x; S.dsbuf[2 * tid + 1] = v.y; }
        else { S.fv3[2 * (tid - 32)] = v.x; S.fv3[2 * (tid - 32) + 1] = v.y; }
      }
      __syncthreads();
      if (tid < 64) S.fut_acc[tid] += S.fv3[tid];
      {   // fusion_in = relu(fus_W @ ds + fus_b), per-thread 2 rows from VGPRs
        float a0 = fusb0, a1 = fusb1;
        #pragma unroll
        for (int o = 0; o < 64; ++o){
          float d = S.dsbuf[o];
          a0 = fmaf(bfu((u16t)(fw[o] & 0xffff)), d, a0);
          a1 = fmaf(bfu((u16t)(fw[o] >> 16)),    d, a1);
        }
        S.xs[2 * tid]     = fmaxf(a0, 0.f);
        S.xs[2 * tid + 1] = fmaxf(a1, 0.f);
      }
      __syncthreads();
      float accB = lds_dot_bf16(S.decW + hw * 2048, S.xs, 1024, lane);
      {
        float a = accA + accB + S.bias_d[hw];
        if (lane == 0) S.g16[hw] = a;
      }
      __syncthreads();
      if (tid < 4){
        float gi = sigm(S.g16[tid]), gf = sigm(S.g16[4 + tid]),
              gg = tanhx(S.g16[8 + tid]), go = sigm(S.g16[12 + tid]);
        float c = gf * S.dcx_s[tid] + gi * gg;
        float h = go * tanhx(c);
        stp(ws + (di == 2 ? DD2 : DD3) + par * 2048, 4 * w + tid, h, ep);
      }
    }
    // ph2 producers: poll DD3, compute ds3 (-> out) and f3 (-> next R1's SFF)
    if (w >= 32 && w < 40){
      {
        float2 v = poll2(ws + DD3 + par * 2048 + tid * 4, ep, &S.bail);
        S.xs[1024 + 2 * tid] = v.x; S.xs[1025 + 2 * tid] = v.y;
      }
      __syncthreads();
      produce_sf<F32>(p, ws, S, 2, par, ep, t, w, hw, lane);
    }
  }
}

__global__ __launch_bounds__(NTHR, 2)
void trn_persist(Params p){
  __shared__ SharedMem S;
  // ---- runtime input-dtype detection from X's bit patterns ----
  if (threadIdx.x == 0){ S.bail = 0; S.badcnt = 0; }
  __syncthreads();
  if (threadIdx.x < 256){
    u16t u = ((const u16t*)p.X)[threadIdx.x];
    int e = (u >> 7) & 0xff;
    if (e == 0 || e >= 141) atomicAdd(&S.badcnt, 1);
  }
  __syncthreads();
  if (S.badcnt >= 3) run<true>(p, S);
  else               run<false>(p, S);
}

extern "C" void kernel_launch(void* const* d_in, const int* in_sizes, int n_in,
                              void* d_out, int out_size, void* d_ws, size_t ws_size,
                              hipStream_t stream){
  Params P;
  P.X      = d_in[0];
  P.eWih   = d_in[1];
  P.eWhh   = d_in[2];
  P.ebih   = d_in[3];
  P.ebhh   = d_in[4];
  P.dWih   = d_in[5];
  P.dWhh   = d_in[6];
  P.dbih   = d_in[7];
  P.dbhh   = d_in[8];
  P.hxW    = d_in[9];
  P.hxb    = d_in[10];
  P.cxW    = d_in[11];
  P.cxb    = d_in[12];
  P.fusW   = d_in[13];
  P.fusb_g = d_in[14];
  P.futW   = d_in[15];
  P.futb_g = d_in[16];
  P.clsW   = d_in[17];
  P.clsb_g = d_in[18];
  P.ws     = (float*)d_ws;
  P.out    = d_out;

  void* args[] = { &P };
  hipLaunchCooperativeKernel((void*)trn_persist, dim3(NWG), dim3(NTHR),
                             args, 0, stream);
}